// Round 5
// baseline (3406.412 us; speedup 1.0000x reference)
//
#include <hip/hip_runtime.h>
#include <hip/hip_bf16.h>

// TaylorMap, symmetric-packed quadratic form.
// x_{t+1} = x_t + W0 + W1^T x + sum_{i<=j} x_i x_j (W2[i,j,:]+W2[j,i,:]) , 7 steps.
// R5: wave roles back to (d-tile t, batch-half h) -- R1's register shape
// (112 arch VGPR, zero spill, proven) -- but with the triangular symmetric
// pack kept: row i needs slices j in [16*(i>>4),128), c(i)=8-(i>>4) MFMAs,
// 584 MFMAs/wave/step vs R1's 1040. No parity merge, no sc_lds.
// Cost: the h-wave pair reads the same A stream twice per CU (accepted --
// that redundancy is what keeps bfrag at 8 frags and arch regs <= 128).
// R2/R3/R4 post-mortem: arch-VGPR budget is pinned at 128 regardless of
// __launch_bounds__(...,2) / amdgpu_waves_per_eu(2); demand beyond it spills
// to scratch at GB/s scale. Fit 128 instead of fighting it.

#define DSTATE 128
#define BATCH  16384
#define NSTEPS 7
#define BT     64
#define NSL    584          // slices per d-tile: 576 sym-quad + 8 linear

typedef __attribute__((ext_vector_type(8)))  short  short8;   // 8 bf16 = 4 VGPRs
typedef __attribute__((ext_vector_type(16))) float  f32x16;   // MFMA 32x32 C/D

__device__ __forceinline__ unsigned short f2bf(float f){
    unsigned int u = __float_as_uint(f);
    u += 0x7fff + ((u >> 16) & 1);          // RNE
    return (unsigned short)(u >> 16);
}

// Pack symmetric-folded W into bf16 MFMA-A fragments, triangular row lengths.
// Stream order per d-tile t: rows 0..127 ascending (slices sl(i)..7), then the
// linear (W1) row. Fragment layout: A[m][k], m=lane&31 -> d=32t+m,
// k=(lane>>5)*8+e -> j=16*s+k.
__global__ void prep_kernel(const float* __restrict__ W, short8* __restrict__ A){
    int gid = blockIdx.x * 256 + threadIdx.x;
    const int ntotal = 4 * 129 * 8 * 64;
    if (gid >= ntotal) return;
    int lane = gid & 63; int r = gid >> 6;
    int s = r & 7;  r >>= 3;
    int row = r % 129;
    int t   = r / 129;
    int d  = t * 32 + (lane & 31);
    int kb = (lane >> 5) * 8;
    int dst;
    if (row < 128){
        int sl = row >> 4;
        if (s < sl) return;                  // row i uses slices sl..7 only
        int off = 16 * (8 * sl - (sl * (sl - 1)) / 2) + (row & 15) * (8 - sl);
        dst = t * NSL + off + (s - sl);
    } else {
        dst = t * NSL + 576 + s;             // linear row last
    }
    union { short8 v; unsigned short u[8]; } fr;
#pragma unroll
    for (int e = 0; e < 8; ++e){
        int j = s * 16 + kb + e;
        float v;
        if (row < 128){
            if      (j < row)  v = 0.0f;
            else if (j == row) v = W[(129 + 128 * row + j) * 128 + d];
            else               v = W[(129 + 128 * row + j) * 128 + d]
                                 + W[(129 + 128 * j + row) * 128 + d];
        } else {
            v = W[(1 + j) * 128 + d];
        }
        fr.u[e] = f2bf(v);
    }
    A[(size_t)dst * 64 + lane] = fr.v;
}

__global__ __launch_bounds__(512, 2)
void taylor_kernel(const float* __restrict__ X, const float* __restrict__ W,
                   const float* __restrict__ tini, const float* __restrict__ lini,
                   const short8* __restrict__ A, float* __restrict__ out)
{
    __shared__ float x_lds[DSTATE * BT];       // fp32 master state, [d][b]
    __shared__ float w0_lds[DSTATE];

    const int tid  = threadIdx.x;
    const int lane = tid & 63;
    const int w    = tid >> 6;
    const int t    = w & 3;                    // d-tile (32 dims)
    const int h    = w >> 2;                   // batch half (32 cols)
    const int ln   = lane & 31;
    const int hi   = lane >> 5;
    const int col  = h * 32 + ln;              // this lane's batch column
    const int b0   = blockIdx.x * BT;

    // ---- init x0 = [X | t_init | l_init] ----
#pragma unroll
    for (int it = 0; it < 16; ++it){
        int entry = tid + it * 512;            // entry = b*128 + d
        int b = entry >> 7, d = entry & 127;
        float v;
        if      (d < 120) v = X[(b0 + b) * 120 + d];
        else if (d < 124) v = tini[d - 120];
        else              v = lini[d - 124];
        x_lds[d * BT + b] = v;
    }
    if (tid < DSTATE) w0_lds[tid] = W[tid];

    const short8* const Aw = A + (size_t)(t * NSL) * 64 + lane;

#pragma unroll 1
    for (int step = 0; step < NSTEPS; ++step){
        __syncthreads();                       // (A) x_lds stable for this step

        // ---- B fragments for own half (8 frags = 32 VGPRs) ----
        short8 bfrag[8];
#pragma unroll
        for (int s = 0; s < 8; ++s){
            union { short8 v; unsigned short u[8]; } fr;
#pragma unroll
            for (int e = 0; e < 8; ++e){
                int j = s * 16 + hi * 8 + e;
                fr.u[e] = f2bf(x_lds[j * BT + col]);
            }
            bfrag[s] = fr.v;
        }

        // ---- acc = x_old + W0 (residual + bias folded) ----
        f32x16 acc;
#pragma unroll
        for (int r = 0; r < 16; ++r){
            int d = 32 * t + (r & 3) + 8 * (r >> 2) + 4 * hi;
            acc[r] = x_lds[d * BT + col] + w0_lds[d];
        }

        // ---- triangular row loop, A double-buffered, static chain lengths ----
        const short8* ap = Aw;
        short8 abuf[2][8];
#pragma unroll
        for (int s = 0; s < 8; ++s) abuf[0][s] = ap[s * 64];
        ap += 8 * 64;
        int irow = 0;

#define ROW(C, SL, CUR, NXT, PFC)                                               \
        {                                                                       \
            _Pragma("unroll")                                                   \
            for (int s = 0; s < (PFC); ++s) abuf[NXT][s] = ap[s * 64];          \
            ap += (PFC) * 64;                                                   \
            float s0 = x_lds[irow * BT + col];                                  \
            f32x16 Y = {};                                                      \
            _Pragma("unroll")                                                   \
            for (int s = 0; s < (C); ++s)                                       \
                Y = __builtin_amdgcn_mfma_f32_32x32x16_bf16(abuf[CUR][s], bfrag[(SL) + s], Y, 0, 0, 0); \
            acc += s0 * Y;                                                      \
            irow += 1;                                                          \
        }

        // 16 rows per block; last row prefetches the next block's width
#define BLOCK(C, SL)                                                            \
        for (int pr = 0; pr < 7; ++pr){ ROW(C, SL, 0, 1, C) ROW(C, SL, 1, 0, C) } \
        ROW(C, SL, 0, 1, C)                                                     \
        ROW(C, SL, 1, 0, ((C) > 1 ? (C) - 1 : 8))

        BLOCK(8, 0) BLOCK(7, 1) BLOCK(6, 2) BLOCK(5, 3)
        BLOCK(4, 4) BLOCK(3, 5) BLOCK(2, 6) BLOCK(1, 7)
#undef ROW
#undef BLOCK

        // linear (W1) row, scale 1 (abuf[0] holds its 8 slices)
        {
            f32x16 Y = {};
#pragma unroll
            for (int s = 0; s < 8; ++s)
                Y = __builtin_amdgcn_mfma_f32_32x32x16_bf16(abuf[0][s], bfrag[s], Y, 0, 0, 0);
            acc += Y;
        }

        __syncthreads();                       // (B) all x_lds reads done
        if (step < NSTEPS - 1){
#pragma unroll
            for (int r = 0; r < 16; ++r){
                int d = 32 * t + (r & 3) + 8 * (r >> 2) + 4 * hi;
                x_lds[d * BT + col] = acc[r];
            }
        } else if (t == 3 && hi == 0){
            // out dims 120..123 -> tile 3, regs 12..15 @ hi==0
            *(float4*)(out + (size_t)(b0 + col) * 4) =
                make_float4(acc[12], acc[13], acc[14], acc[15]);
        }
    }
}

extern "C" void kernel_launch(void* const* d_in, const int* in_sizes, int n_in,
                              void* d_out, int out_size, void* d_ws, size_t ws_size,
                              hipStream_t stream)
{
    const float* X  = (const float*)d_in[0];
    const float* W  = (const float*)d_in[1];
    const float* ti = (const float*)d_in[2];
    const float* li = (const float*)d_in[3];
    float* out      = (float*)d_out;
    short8* A       = (short8*)d_ws;           // 4*584*64*16 B = 2.39 MB

    const int ntotal = 4 * 129 * 8 * 64;
    prep_kernel<<<(ntotal + 255) / 256, 256, 0, stream>>>(W, A);
    taylor_kernel<<<BATCH / BT, 512, 0, stream>>>(X, W, ti, li, A, out);
}

// Round 6
// 380.030 us; speedup vs baseline: 8.9635x; 8.9635x over previous
//
#include <hip/hip_runtime.h>
#include <hip/hip_bf16.h>

// TaylorMap, symmetric-packed quadratic form, UNIFORM-9 PAIR STREAM.
// x_{t+1} = x_t + W0 + W1^T x + sum_{i<=j} x_i x_j (W2[i,j,:]+W2[j,i,:]) , 7 steps.
// Identity: sl(i)=i>>4 satisfies sl(p)+sl(127-p)=7, so pair (p,127-p) costs
// exactly c(p)+c(127-p) = 9 MFMA slices for every p -> uniform loop body.
// Stream per d-tile: 64 pairs x 9 slices + linear row (8) + zero pad (1) = 585.
// 584 real MFMAs/wave/step vs R1's 1040 (1.78x), R1's register shape kept.
// R2-R5 post-mortem: any giant straight-line step body makes the scheduler
// hoist loads -> live-range explosion -> GB-scale scratch spill, regardless of
// launch-bounds hints. The fix is R1's compact `#pragma unroll 2` rolled loop;
// uniform-9 pairs are what make the triangular pack expressible that way.

#define DSTATE 128
#define BATCH  16384
#define NSTEPS 7
#define BT     64
#define NSL    585          // slices per d-tile: 64*9 pair + 8 linear + 1 pad

typedef __attribute__((ext_vector_type(8)))  short  short8;   // 8 bf16 = 4 VGPRs
typedef __attribute__((ext_vector_type(16))) float  f32x16;   // MFMA 32x32 C/D

__device__ __forceinline__ unsigned short f2bf(float f){
    unsigned int u = __float_as_uint(f);
    u += 0x7fff + ((u >> 16) & 1);          // RNE
    return (unsigned short)(u >> 16);
}

// Pack symmetric-folded W into bf16 MFMA-A fragments, uniform-9 pair stream.
// Pair p occupies positions 9p..9p+8: first c_a=8-(p>>4) slices are row p
// (j-blocks p>>4 .. 7), remaining 1+(p>>4) are row 127-p (j-blocks 7-(p>>4)..7).
// Fragment layout: A[m][k], m=lane&31 -> d=32t+m, k=(lane>>5)*8+e -> j=16*s+k.
__global__ void prep_kernel(const float* __restrict__ W, short8* __restrict__ A){
    int gid = blockIdx.x * 256 + threadIdx.x;
    const int ntotal = 4 * 130 * 8 * 64;
    if (gid >= ntotal) return;
    int lane = gid & 63; int r = gid >> 6;
    int s = r & 7;  r >>= 3;
    int row = r % 130;
    int t   = r / 130;
    int d  = t * 32 + (lane & 31);
    int kb = (lane >> 5) * 8;
    int dst;
    bool zero = false;
    if (row < 64){
        int sl = row >> 4;
        if (s < sl) return;                    // row uses j-blocks sl..7
        dst = t * NSL + 9 * row + (s - sl);
    } else if (row < 128){
        int p  = 127 - row;                    // partner pair index
        int sl = row >> 4;
        if (s < sl) return;
        int ca = 8 - (p >> 4);                 // partner-row slice count
        dst = t * NSL + 9 * p + ca + (s - sl);
    } else if (row == 128){
        dst = t * NSL + 576 + s;               // linear (W1) row
    } else {
        if (s) return;                         // zero pad slice (prefetch target)
        dst = t * NSL + 584;
        zero = true;
    }
    union { short8 v; unsigned short u[8]; } fr;
#pragma unroll
    for (int e = 0; e < 8; ++e){
        int j = s * 16 + kb + e;
        float v;
        if (zero) v = 0.0f;
        else if (row < 128){
            if      (j < row)  v = 0.0f;
            else if (j == row) v = W[(129 + 128 * row + j) * 128 + d];
            else               v = W[(129 + 128 * row + j) * 128 + d]
                                 + W[(129 + 128 * j + row) * 128 + d];
        } else {
            v = W[(1 + j) * 128 + d];
        }
        fr.u[e] = f2bf(v);
    }
    A[(size_t)dst * 64 + lane] = fr.v;
}

__global__ __launch_bounds__(512, 2)
void taylor_kernel(const float* __restrict__ X, const float* __restrict__ W,
                   const float* __restrict__ tini, const float* __restrict__ lini,
                   const short8* __restrict__ A, float* __restrict__ out)
{
    __shared__ float x_lds[DSTATE * BT];       // fp32 master state, [d][b]
    __shared__ float w0_lds[DSTATE];

    const int tid  = threadIdx.x;
    const int lane = tid & 63;
    const int w    = tid >> 6;
    const int t    = w & 3;                    // d-tile (32 dims)
    const int h    = w >> 2;                   // batch half (32 cols)
    const int ln   = lane & 31;
    const int hi   = lane >> 5;
    const int col  = h * 32 + ln;              // this lane's batch column
    const int b0   = blockIdx.x * BT;

    // ---- init x0 = [X | t_init | l_init] ----
#pragma unroll
    for (int it = 0; it < 16; ++it){
        int entry = tid + it * 512;            // entry = b*128 + d
        int b = entry >> 7, d = entry & 127;
        float v;
        if      (d < 120) v = X[(b0 + b) * 120 + d];
        else if (d < 124) v = tini[d - 120];
        else              v = lini[d - 124];
        x_lds[d * BT + b] = v;
    }
    if (tid < DSTATE) w0_lds[tid] = W[tid];

    const short8* const Aw = A + (size_t)(t * NSL) * 64 + lane;

#pragma unroll 1
    for (int step = 0; step < NSTEPS; ++step){
        __syncthreads();                       // (A) x_lds stable for this step

        // ---- B fragments for own half (8 frags = 32 VGPRs) ----
        short8 bfrag[8];
#pragma unroll
        for (int s = 0; s < 8; ++s){
            union { short8 v; unsigned short u[8]; } fr;
#pragma unroll
            for (int e = 0; e < 8; ++e){
                int j = s * 16 + hi * 8 + e;
                fr.u[e] = f2bf(x_lds[j * BT + col]);
            }
            bfrag[s] = fr.v;
        }

        // ---- acc = x_old + W0 (residual + bias folded) ----
        f32x16 acc;
#pragma unroll
        for (int r = 0; r < 16; ++r){
            int d = 32 * t + (r & 3) + 8 * (r >> 2) + 4 * hi;
            acc[r] = x_lds[d * BT + col] + w0_lds[d];
        }

        // ---- pair loop: 4 compact rolled loops, uniform 9-slice prefetch ----
        const short8* ap = Aw;
        short8 abuf[2][9];
#pragma unroll
        for (int s = 0; s < 9; ++s) abuf[0][s] = ap[s * 64];
        ap += 9 * 64;

        // pair p = 16*BK+q: rows (p, 127-p); chains C_A=8-BK, C_B=1+BK.
        // Every iteration prefetches exactly 9; pair 63's prefetch is the
        // linear row + pad (positions 576..584) -- no boundary conditional.
#define PAIRS(BK)                                                               \
        _Pragma("unroll 2")                                                     \
        for (int q = 0; q < 16; ++q){                                           \
            const int cur = q & 1, nxt = cur ^ 1;                               \
            _Pragma("unroll")                                                   \
            for (int s = 0; s < 9; ++s) abuf[nxt][s] = ap[s * 64];              \
            ap += 9 * 64;                                                       \
            const int p = 16 * (BK) + q;                                        \
            float s0 = x_lds[p * BT + col];                                     \
            float s1 = x_lds[(127 - p) * BT + col];                             \
            f32x16 Y = {};                                                      \
            _Pragma("unroll")                                                   \
            for (int s = 0; s < 8 - (BK); ++s)                                  \
                Y = __builtin_amdgcn_mfma_f32_32x32x16_bf16(abuf[cur][s], bfrag[(BK) + s], Y, 0, 0, 0); \
            acc += s0 * Y;                                                      \
            f32x16 Z = {};                                                      \
            _Pragma("unroll")                                                   \
            for (int s = 0; s < 1 + (BK); ++s)                                  \
                Z = __builtin_amdgcn_mfma_f32_32x32x16_bf16(abuf[cur][8 - (BK) + s], bfrag[7 - (BK) + s], Z, 0, 0, 0); \
            acc += s1 * Z;                                                      \
        }

        PAIRS(0) PAIRS(1) PAIRS(2) PAIRS(3)
#undef PAIRS

        // linear (W1) row, scale 1 (abuf[0] holds positions 576..583)
        {
            f32x16 Y = {};
#pragma unroll
            for (int s = 0; s < 8; ++s)
                Y = __builtin_amdgcn_mfma_f32_32x32x16_bf16(abuf[0][s], bfrag[s], Y, 0, 0, 0);
            acc += Y;
        }

        __syncthreads();                       // (B) all x_lds reads done
        if (step < NSTEPS - 1){
#pragma unroll
            for (int r = 0; r < 16; ++r){
                int d = 32 * t + (r & 3) + 8 * (r >> 2) + 4 * hi;
                x_lds[d * BT + col] = acc[r];
            }
        } else if (t == 3 && hi == 0){
            // out dims 120..123 -> tile 3, regs 12..15 @ hi==0
            *(float4*)(out + (size_t)(b0 + col) * 4) =
                make_float4(acc[12], acc[13], acc[14], acc[15]);
        }
    }
}

extern "C" void kernel_launch(void* const* d_in, const int* in_sizes, int n_in,
                              void* d_out, int out_size, void* d_ws, size_t ws_size,
                              hipStream_t stream)
{
    const float* X  = (const float*)d_in[0];
    const float* W  = (const float*)d_in[1];
    const float* ti = (const float*)d_in[2];
    const float* li = (const float*)d_in[3];
    float* out      = (float*)d_out;
    short8* A       = (short8*)d_ws;           // 4*585*64*16 B = 2.40 MB

    const int ntotal = 4 * 130 * 8 * 64;
    prep_kernel<<<(ntotal + 255) / 256, 256, 0, stream>>>(W, A);
    taylor_kernel<<<BATCH / BT, 512, 0, stream>>>(X, W, ti, li, A, out);
}